// Round 15
// baseline (2413.832 us; speedup 1.0000x reference)
//
#include <hip/hip_runtime.h>

typedef _Float16 f16x8 __attribute__((ext_vector_type(8)));
typedef _Float16 f16x2 __attribute__((ext_vector_type(2)));
typedef float f32x4 __attribute__((ext_vector_type(4)));

#define DEV __device__ __forceinline__

struct alignas(16) H8 { _Float16 h[8]; };
struct alignas(8)  H4 { _Float16 h[4]; };

union U8 { f16x2 v[4]; f16x8 x; H8 h; };
union U4 { f16x2 v[2]; H4 h; unsigned int u[2]; };

DEV f32x4 mfma16(f16x8 a, f16x8 b, f32x4 c) {
  return __builtin_amdgcn_mfma_f32_16x16x32_f16(a, b, c, 0, 0, 0);
}

DEV f16x2 pkrtz(float a, float b) {
  return __builtin_bit_cast(f16x2, __builtin_amdgcn_cvt_pkrtz(a, b));
}

// 8-wide f32 -> fp16 hi/lo split via packed converts (hi RTZ; lo captures residual)
DEV void split8v(const float* t, f16x8& hi, f16x8& lo) {
  U8 H_, L_;
  #pragma unroll
  for (int j = 0; j < 4; ++j) {
    f16x2 hh = pkrtz(t[2*j], t[2*j+1]);
    float r0 = t[2*j]   - (float)hh[0];
    float r1 = t[2*j+1] - (float)hh[1];
    H_.v[j] = hh;
    L_.v[j] = pkrtz(r0, r1);
  }
  hi = H_.x; lo = L_.x;
}

// pair split: 2 f32 -> hi f16x2 (RTZ) + lo f16x2 (residual)
DEV void packpair(float a, float b, f16x2& hi, f16x2& lo) {
  f16x2 hh = pkrtz(a, b);
  lo = pkrtz(a - (float)hh[0], b - (float)hh[1]);
  hi = hh;
}

// read 8 fp16 from 72-byte-stride bT layout (two b64 loads, 8B aligned)
DEV f16x8 frag_b36(const _Float16* b, int n, int kc) {
  const unsigned long long* p = (const unsigned long long*)(b + n*36 + kc*8);
  union { unsigned long long u[2]; f16x8 v; } r;
  r.u[0] = p[0]; r.u[1] = p[1];
  return r.v;
}

DEV float block_sum(float v, volatile float* red, int tid) {
  #pragma unroll
  for (int mm = 1; mm < 64; mm <<= 1) v += __shfl_xor(v, mm);
  if ((tid & 63) == 0) red[tid >> 6] = v;
  __syncthreads();
  return red[0] + red[1] + red[2] + red[3];
}

// ---------------- RMSNorm (input) -> fp16 hi/lo split ----------------
__global__ __launch_bounds__(256) void k_rmsnorm_split(
    const float* __restrict__ x, const float* __restrict__ w,
    _Float16* __restrict__ hi, _Float16* __restrict__ lo) {
  __shared__ float red[4];
  int row = blockIdx.x, tid = threadIdx.x;
  const float* xr = x + (size_t)row*2048 + tid*8;
  float xs[8];
  *(float4*)&xs[0] = *(const float4*)xr;
  *(float4*)&xs[4] = *(const float4*)(xr + 4);
  float ss = 0.f;
  #pragma unroll
  for (int j = 0; j < 8; ++j) ss += xs[j]*xs[j];
  float tot = block_sum(ss, red, tid);
  float sc = 1.0f / sqrtf(tot*(1.0f/2048.0f) + 1e-5f);
  const float* wr = w + tid*8;
  H8 ph, pl;
  #pragma unroll
  for (int j = 0; j < 8; ++j) {
    float o = xs[j]*sc*wr[j];
    _Float16 hh = (_Float16)o;
    ph.h[j] = hh; pl.h[j] = (_Float16)(o - (float)hh);
  }
  *(H8*)(hi + (size_t)row*2048 + tid*8) = ph;
  *(H8*)(lo + (size_t)row*2048 + tid*8) = pl;
}

// ---------------- dense split GEMM, K-split + atomic epilogue ----------------
// B staged via float4 row-contiguous loads (4 cols x 4 rows per thread).
__global__ __launch_bounds__(256) void k_gemm_ks(
    const _Float16* __restrict__ Ahi, const _Float16* __restrict__ Alo,
    const float* __restrict__ B, int N, int K,
    float* __restrict__ C) {
  const int tid = threadIdx.x;
  const int l = tid & 63, w = tid >> 6;
  const int wm = w >> 1, wn = w & 1;
  const int row0 = blockIdx.y * 128, col0 = blockIdx.x * 128;
  const int kz = K / gridDim.z;
  const int kbase = blockIdx.z * kz;

  __shared__ _Float16 aHi[128*32], aLo[128*32];
  __shared__ _Float16 bHi[128*36], bLo[128*36];

  f32x4 acc[4][4] = {};

  const int rS = tid >> 1, khalf = tid & 1;
  const int cg = tid & 31, rg = tid >> 5;   // B: 4 cols (cg*4), 4 rows (rg*4)

  for (int k0 = kbase; k0 < kbase + kz; k0 += 32) {
    __syncthreads();
    { // stage A (chunk-XOR swizzled)
      int c0 = khalf*2;
      int d0 = rS*32 + ((c0    ) ^ (rS&3))*8;
      int d1 = rS*32 + ((c0 + 1) ^ (rS&3))*8;
      const _Float16* ah = Ahi + (size_t)(row0 + rS)*K + k0 + khalf*16;
      const _Float16* al = Alo + (size_t)(row0 + rS)*K + k0 + khalf*16;
      *(H8*)&aHi[d0] = *(const H8*)ah;
      *(H8*)&aHi[d1] = *(const H8*)(ah + 8);
      *(H8*)&aLo[d0] = *(const H8*)al;
      *(H8*)&aLo[d1] = *(const H8*)(al + 8);
    }
    { // stage B: 4 float4 row-contiguous loads, split + transpose-pack
      const float* bp = B + (size_t)(k0 + rg*4)*N + col0 + cg*4;
      float4 v0 = *(const float4*)bp;
      float4 v1 = *(const float4*)(bp + N);
      float4 v2 = *(const float4*)(bp + 2*(size_t)N);
      float4 v3 = *(const float4*)(bp + 3*(size_t)N);
      const float* r0 = (const float*)&v0;
      const float* r1 = (const float*)&v1;
      const float* r2 = (const float*)&v2;
      const float* r3 = (const float*)&v3;
      #pragma unroll
      for (int j = 0; j < 4; ++j) {
        U4 hu, lu;
        packpair(r0[j], r1[j], hu.v[0], lu.v[0]);
        packpair(r2[j], r3[j], hu.v[1], lu.v[1]);
        int ei = (cg*4 + j)*36 + rg*4;
        *(H4*)&bHi[ei] = hu.h;
        *(H4*)&bLo[ei] = lu.h;
      }
    }
    __syncthreads();
    { // compute
      const int kc = l >> 4;
      f16x8 ah[4], al4[4];
      #pragma unroll
      for (int m = 0; m < 4; ++m) {
        int mr = wm*64 + m*16 + (l & 15);
        int cc = (kc ^ (mr & 3))*8;
        ah[m]  = *(const f16x8*)&aHi[mr*32 + cc];
        al4[m] = *(const f16x8*)&aLo[mr*32 + cc];
      }
      #pragma unroll
      for (int n = 0; n < 4; ++n) {
        int nr = wn*64 + n*16 + (l & 15);
        f16x8 bh = frag_b36(bHi, nr, kc);
        f16x8 bl = frag_b36(bLo, nr, kc);
        #pragma unroll
        for (int m = 0; m < 4; ++m) {
          acc[m][n] = mfma16(ah[m],  bh, acc[m][n]);
          acc[m][n] = mfma16(ah[m],  bl, acc[m][n]);
          acc[m][n] = mfma16(al4[m], bh, acc[m][n]);
        }
      }
    }
  }
  #pragma unroll
  for (int m = 0; m < 4; ++m)
    #pragma unroll
    for (int n = 0; n < 4; ++n)
      #pragma unroll
      for (int r = 0; r < 4; ++r) {
        int row = row0 + wm*64 + m*16 + (l>>4)*4 + r;
        int col = col0 + wn*64 + n*16 + (l&15);
        atomicAdd(&C[(size_t)row*N + col], acc[m][n][r]);
      }
}

// ---------------- RoPE (neox, in-place, f32) ----------------
__global__ __launch_bounds__(256) void k_rope(
    float* __restrict__ buf, const int* __restrict__ pos, int nh) {
  int s = blockIdx.x;
  int hh = blockIdx.y*4 + (threadIdx.x >> 6);
  int d = threadIdx.x & 63;
  float p = (float)pos[s];
  double ex = ((double)(2*d)/128.0) * 9.210340371976184; // log(10000)
  float pw = (float)exp(ex);
  float inv = 1.0f / pw;
  float ang = p * inv;
  float cs = cosf(ang), sn = sinf(ang);
  float* b = buf + (size_t)s*(nh*128) + hh*128 + d;
  float x1 = b[0], x2 = b[64];
  b[0]  = x1*cs - x2*sn;
  b[64] = x2*cs + x1*sn;
}

// ---------------- flash attention, fp16x2 split, causal GQA ----------------
__global__ __launch_bounds__(256) void k_attn(
    const float* __restrict__ q, const float* __restrict__ k,
    const float* __restrict__ v,
    _Float16* __restrict__ o_hi, _Float16* __restrict__ o_lo) {
  const int qt = gridDim.x - 1 - blockIdx.x;  // heavy causal tiles first
  const int h = blockIdx.y;
  const int tid = threadIdx.x, l = tid & 63, w = tid >> 6;
  const int qb = qt*64, qw = qb + w*16;
  const int kvh = h >> 2;

  __shared__ _Float16 kHi[32*128], kLo[32*128];
  __shared__ _Float16 vHi[128*32], vLo[128*32];  // transposed [d][kv]
  __shared__ _Float16 pHi[4][16*40], pLo[4][16*40];

  f16x8 qh[4], ql[4];
  {
    int qrow = qw + (l & 15);
    const float* qp = q + (size_t)qrow*2048 + h*128 + (l>>4)*8;
    #pragma unroll
    for (int c = 0; c < 4; ++c) {
      float t[8];
      *(float4*)&t[0] = *(const float4*)(qp + c*32);
      *(float4*)&t[4] = *(const float4*)(qp + c*32 + 4);
      split8v(t, qh[c], ql[c]);
    }
  }

  float mrun[4], lrun[4];
  f32x4 oacc[8] = {};
  #pragma unroll
  for (int r = 0; r < 4; ++r) { mrun[r] = -1e30f; lrun[r] = 0.f; }

  const int srow = tid >> 3, sc = (tid & 7)*2;

  for (int kv0 = 0; kv0 <= qb + 32; kv0 += 32) {
    __syncthreads();
    { // stage K (row-major, XOR swizzle) and V (transposed, XOR swizzle)
      const float* kp = k + (size_t)(kv0 + srow)*512 + kvh*128 + sc*8;
      const float* vp = v + (size_t)(kv0 + srow)*512 + kvh*128 + sc*8;
      #pragma unroll
      for (int cc = 0; cc < 2; ++cc) {
        int c = sc + cc;
        float tk[8];
        *(float4*)&tk[0] = *(const float4*)(kp + cc*8);
        *(float4*)&tk[4] = *(const float4*)(kp + cc*8 + 4);
        f16x8 hx, lx;
        split8v(tk, hx, lx);
        int di = srow*128 + (c ^ (srow & 7))*8;
        *(H8*)&kHi[di] = *(const H8*)&hx;
        *(H8*)&kLo[di] = *(const H8*)&lx;
        float tv_[8];
        *(float4*)&tv_[0] = *(const float4*)(vp + cc*8);
        *(float4*)&tv_[4] = *(const float4*)(vp + cc*8 + 4);
        #pragma unroll
        for (int j = 0; j < 8; ++j) {
          float x = tv_[j];
          _Float16 hh = (_Float16)x;
          _Float16 ll = (_Float16)(x - (float)hh);
          int d = c*8 + j;
          int vi = d*32 + (((srow>>3) ^ (d&3)))*8 + (srow & 7);
          vHi[vi] = hh; vLo[vi] = ll;
        }
      }
    }
    __syncthreads();
    if (kv0 <= qw + 15) {
      f32x4 s[2] = {};
      #pragma unroll
      for (int nt = 0; nt < 2; ++nt) {
        int krow = nt*16 + (l & 15);
        #pragma unroll
        for (int c = 0; c < 4; ++c) {
          int ch = (c*4 + (l>>4)) ^ (krow & 7);
          f16x8 bh = *(const f16x8*)&kHi[krow*128 + ch*8];
          f16x8 bl = *(const f16x8*)&kLo[krow*128 + ch*8];
          s[nt] = mfma16(qh[c], bh, s[nt]);
          s[nt] = mfma16(qh[c], bl, s[nt]);
          s[nt] = mfma16(ql[c], bh, s[nt]);
        }
      }
      const float SC = 0.08838834764831845f;
      float sv[2][4];
      #pragma unroll
      for (int nt = 0; nt < 2; ++nt)
        #pragma unroll
        for (int r = 0; r < 4; ++r) {
          float val = s[nt][r]*SC;
          int qg = qw + (l>>4)*4 + r;
          int kg = kv0 + nt*16 + (l & 15);
          sv[nt][r] = (kg > qg) ? -1e30f : val;
        }
      float tm[4];
      #pragma unroll
      for (int r = 0; r < 4; ++r) tm[r] = fmaxf(sv[0][r], sv[1][r]);
      #pragma unroll
      for (int mm = 1; mm < 16; mm <<= 1)
        #pragma unroll
        for (int r = 0; r < 4; ++r) tm[r] = fmaxf(tm[r], __shfl_xor(tm[r], mm));
      float alpha[4], rs[4];
      #pragma unroll
      for (int r = 0; r < 4; ++r) {
        float mn = fmaxf(mrun[r], tm[r]);
        alpha[r] = expf(mrun[r] - mn);
        mrun[r] = mn;
      }
      float pv[2][4];
      #pragma unroll
      for (int nt = 0; nt < 2; ++nt)
        #pragma unroll
        for (int r = 0; r < 4; ++r) pv[nt][r] = expf(sv[nt][r] - mrun[r]);
      #pragma unroll
      for (int r = 0; r < 4; ++r) rs[r] = pv[0][r] + pv[1][r];
      #pragma unroll
      for (int mm = 1; mm < 16; mm <<= 1)
        #pragma unroll
        for (int r = 0; r < 4; ++r) rs[r] += __shfl_xor(rs[r], mm);
      #pragma unroll
      for (int r = 0; r < 4; ++r) lrun[r] = lrun[r]*alpha[r] + rs[r];
      #pragma unroll
      for (int dt = 0; dt < 8; ++dt)
        #pragma unroll
        for (int r = 0; r < 4; ++r) oacc[dt][r] *= alpha[r];
      // P -> per-wave LDS (split), then read back as A-fragments
      #pragma unroll
      for (int nt = 0; nt < 2; ++nt)
        #pragma unroll
        for (int r = 0; r < 4; ++r) {
          float x = pv[nt][r];
          _Float16 hh = (_Float16)x;
          int qr = (l>>4)*4 + r, kc = nt*16 + (l & 15);
          pHi[w][qr*40 + kc] = hh;
          pLo[w][qr*40 + kc] = (_Float16)(x - (float)hh);
        }
      f16x8 pa = *(const f16x8*)&pHi[w][(l&15)*40 + (l>>4)*8];
      f16x8 pb = *(const f16x8*)&pLo[w][(l&15)*40 + (l>>4)*8];
      #pragma unroll
      for (int dt = 0; dt < 8; ++dt) {
        int d = dt*16 + (l & 15);
        int ch = ((l>>4) ^ (d & 3))*8;
        f16x8 vh = *(const f16x8*)&vHi[d*32 + ch];
        f16x8 vl = *(const f16x8*)&vLo[d*32 + ch];
        oacc[dt] = mfma16(pa, vh, oacc[dt]);
        oacc[dt] = mfma16(pa, vl, oacc[dt]);
        oacc[dt] = mfma16(pb, vh, oacc[dt]);
      }
    }
  }
  #pragma unroll
  for (int dt = 0; dt < 8; ++dt)
    #pragma unroll
    for (int r = 0; r < 4; ++r) {
      int qg = qw + (l>>4)*4 + r;
      float ov = oacc[dt][r] / lrun[r];
      _Float16 hh = (_Float16)ov;
      size_t idx = (size_t)qg*2048 + h*128 + dt*16 + (l&15);
      o_hi[idx] = hh;
      o_lo[idx] = (_Float16)(ov - (float)hh);
    }
}

// ---------------- post-attn RMSNorm + gate logits ----------------
__global__ __launch_bounds__(256) void k_postnorm_gate(
    const float* __restrict__ resid, const float* __restrict__ wln,
    const float* __restrict__ wg, _Float16* __restrict__ h2,
    float* __restrict__ logits) {
  __shared__ float red[4];
  __shared__ float red2[4][8];
  int row = blockIdx.x, tid = threadIdx.x;
  const float* xr = resid + (size_t)row*2048 + tid*8;
  float xs[8];
  *(float4*)&xs[0] = *(const float4*)xr;
  *(float4*)&xs[4] = *(const float4*)(xr + 4);
  float ss = 0.f;
  #pragma unroll
  for (int j = 0; j < 8; ++j) ss += xs[j]*xs[j];
  float tot = block_sum(ss, red, tid);
  float sc = 1.0f/sqrtf(tot*(1.0f/2048.0f) + 1e-5f);
  const float* wr = wln + tid*8;
  float hv[8];
  H8 ph;
  #pragma unroll
  for (int j = 0; j < 8; ++j) {
    hv[j] = xs[j]*sc*wr[j];
    ph.h[j] = (_Float16)hv[j];
  }
  *(H8*)(h2 + (size_t)row*2048 + tid*8) = ph;
  float lg[8] = {0,0,0,0,0,0,0,0};
  const float* wgp = wg + (size_t)tid*8*8;
  #pragma unroll
  for (int j = 0; j < 8; ++j)
    #pragma unroll
    for (int e = 0; e < 8; ++e) lg[e] += hv[j]*wgp[j*8 + e];
  #pragma unroll
  for (int mm = 1; mm < 64; mm <<= 1)
    #pragma unroll
    for (int e = 0; e < 8; ++e) lg[e] += __shfl_xor(lg[e], mm);
  if ((tid & 63) == 0)
    #pragma unroll
    for (int e = 0; e < 8; ++e) red2[tid>>6][e] = lg[e];
  __syncthreads();
  if (tid < 8)
    logits[(size_t)row*8 + tid] = red2[0][tid]+red2[1][tid]+red2[2][tid]+red2[3][tid];
}

// ---------------- routing: top-2, slot lists ----------------
__global__ __launch_bounds__(256) void k_route(
    const float* __restrict__ logits, int* __restrict__ counts,
    int* __restrict__ slot_tok, float* __restrict__ slot_w) {
  int t = blockIdx.x*256 + threadIdx.x;
  if (t >= 2048) return;
  float lg[8];
  #pragma unroll
  for (int e = 0; e < 8; ++e) lg[e] = logits[t*8 + e];
  int a = 0; float la = lg[0];
  #pragma unroll
  for (int e = 1; e < 8; ++e) if (lg[e] > la) { la = lg[e]; a = e; }
  int b = -1; float lb = -3e38f;
  #pragma unroll
  for (int e = 0; e < 8; ++e) if (e != a && lg[e] > lb) { lb = lg[e]; b = e; }
  float wa = 1.f/(1.f + expf(lb - la));
  float wb = 1.f - wa;
  int sa = atomicAdd(&counts[a], 1);
  slot_tok[a*2048 + sa] = t; slot_w[a*2048 + sa] = wa;
  int sb = atomicAdd(&counts[b], 1);
  slot_tok[b*2048 + sb] = t; slot_w[b*2048 + sb] = wb;
}

__global__ void k_scan(const int* __restrict__ counts, int* __restrict__ offs) {
  if (threadIdx.x == 0) {
    int o_ = 0;
    #pragma unroll
    for (int e = 0; e < 8; ++e) { offs[e] = o_; o_ += counts[e]; }
  }
}

// ---------------- MoE GEMM1: g = silu(A@w1)*(A@w3) ----------------
// BM=64, dual-BN=64, BK=32, 2-barrier, float4 B stage. bid = e|nt|mt:
// mt innermost so the 32 blocks sharing one 1MB weight slab are co-resident
// (round 14: e|mt|nt doubled FETCH to 1.07GB -> BW-bound).
__global__ __launch_bounds__(256) void k_moe1(
    const _Float16* __restrict__ h2, const float* __restrict__ w1,
    const float* __restrict__ w3, const int* __restrict__ counts,
    const int* __restrict__ offs, const int* __restrict__ slot_tok,
    _Float16* __restrict__ g) {
  int bid = blockIdx.x;
  int e = bid >> 11, nt = (bid >> 5) & 63, mt = bid & 31;
  int cnt = counts[e];
  if (mt*64 >= cnt) return;
  const int tid = threadIdx.x, l = tid & 63, w = tid >> 6;
  const int wm = w >> 1, wn = w & 1;
  __shared__ _Float16 aT[64*32];
  __shared__ _Float16 b1[64*36], b3[64*36];
  const int rS = tid >> 2, kch = tid & 3;   // A: row, 8-f16 chunk
  int slot = mt*64 + rS;
  int tok = (slot < cnt) ? slot_tok[e*2048 + slot] : slot_tok[e*2048];
  const _Float16* arow = h2 + (size_t)tok*2048;
  const int cg = tid & 15, rg = tid >> 4;   // B: 4 cols (cg*4), 2 rows (rg*2)
  const float* w1p = w1 + (size_t)e*2048*4096 + nt*64 + cg*4 + (size_t)rg*2*4096;
  const float* w3p = w3 + (size_t)e*2048*4096 + nt*64 + cg*4 + (size_t)rg*2*4096;
  f32x4 acc1[2][2] = {}, acc3[2][2] = {};
  for (int k0 = 0; k0 < 2048; k0 += 32) {
    __syncthreads();
    { // stage A: one H8 per thread
      *(H8*)&aT[rS*32 + ((kch ^ (rS&3))*8)] = *(const H8*)(arow + k0 + kch*8);
    }
    { // stage B dual: 2 float4 per matrix (rows rg*2, rg*2+1)
      const float* p1 = w1p + (size_t)k0*4096;
      float4 a0 = *(const float4*)p1;
      float4 a1 = *(const float4*)(p1 + 4096);
      const float* p3 = w3p + (size_t)k0*4096;
      float4 c0_ = *(const float4*)p3;
      float4 c1 = *(const float4*)(p3 + 4096);
      const float* x0 = (const float*)&a0;
      const float* x1 = (const float*)&a1;
      const float* y0 = (const float*)&c0_;
      const float* y1 = (const float*)&c1;
      #pragma unroll
      for (int j = 0; j < 4; ++j) {
        int ei = (cg*4 + j)*36 + rg*2;
        *(f16x2*)&b1[ei] = pkrtz(x0[j], x1[j]);
        *(f16x2*)&b3[ei] = pkrtz(y0[j], y1[j]);
      }
    }
    __syncthreads();
    {
      const int kc = l >> 4;
      f16x8 a_[2];
      #pragma unroll
      for (int m = 0; m < 2; ++m) {
        int mr = wm*32 + m*16 + (l & 15);
        a_[m] = *(const f16x8*)&aT[mr*32 + (kc ^ (mr&3))*8];
      }
      #pragma unroll
      for (int n = 0; n < 2; ++n) {
        int nr = wn*32 + n*16 + (l & 15);
        f16x8 bb1 = frag_b36(b1, nr, kc);
        f16x8 bb3 = frag_b36(b3, nr, kc);
        #pragma unroll
        for (int m = 0; m < 2; ++m) {
          acc1[m][n] = mfma16(a_[m], bb1, acc1[m][n]);
          acc3[m][n] = mfma16(a_[m], bb3, acc3[m][n]);
        }
      }
    }
  }
  int ge = offs[e];
  #pragma unroll
  for (int m = 0; m < 2; ++m)
    #pragma unroll
    for (int n = 0; n < 2; ++n)
      #pragma unroll
      for (int r = 0; r < 4; ++r) {
        int srow2 = mt*64 + wm*32 + m*16 + (l>>4)*4 + r;
        if (srow2 < cnt) {
          float x1 = acc1[m][n][r], x3 = acc3[m][n][r];
          float gg = (x1/(1.f + expf(-x1)))*x3;
          int col = nt*64 + wn*32 + n*16 + (l&15);
          g[(size_t)(ge + srow2)*4096 + col] = (_Float16)gg;
        }
      }
}

// ---------------- MoE GEMM2: out[tok] += wgt * (g@w2) ----------------
// BM=64, BN=128, BK=32, 2-barrier, float4 B stage. bid = e|nt|mt (mt inner,
// weight-slab co-residency).
__global__ __launch_bounds__(256) void k_moe2(
    const _Float16* __restrict__ g, const float* __restrict__ w2,
    const int* __restrict__ counts, const int* __restrict__ offs,
    const int* __restrict__ slot_tok, const float* __restrict__ slot_w,
    float* __restrict__ out) {
  int bid = blockIdx.x;
  int e = bid >> 9, nt = (bid >> 5) & 15, mt = bid & 31;
  int cnt = counts[e];
  if (mt*64 >= cnt) return;
  const int tid = threadIdx.x, l = tid & 63, w = tid >> 6;
  const int wm = w >> 1, wn = w & 1;
  __shared__ _Float16 aT[64*32];
  __shared__ _Float16 bT[128*36];
  const int rS = tid >> 2, kch = tid & 3;
  int ge = offs[e];
  int slot = mt*64 + rS;
  const _Float16* arow = g + (size_t)(ge + (slot < cnt ? slot : 0))*4096;
  const int cg = tid & 31, rg = tid >> 5;   // B: 4 cols (cg*4), 4 rows (rg*4)
  const float* w2p = w2 + (size_t)e*4096*2048 + nt*128 + cg*4 + (size_t)rg*4*2048;
  f32x4 acc[2][4] = {};
  for (int k0 = 0; k0 < 4096; k0 += 32) {
    __syncthreads();
    { // stage A
      *(H8*)&aT[rS*32 + ((kch ^ (rS&3))*8)] = *(const H8*)(arow + k0 + kch*8);
    }
    { // stage B: 4 float4 (rows rg*4..+3), transpose-pack to b36
      const float* p = w2p + (size_t)k0*2048;
      float4 v0 = *(const float4*)p;
      float4 v1 = *(const float4*)(p + 2048);
      float4 v2 = *(const float4*)(p + 2*(size_t)2048);
      float4 v3 = *(const float4*)(p + 3*(size_t)2048);
      const float* r0 = (const float*)&v0;
      const float* r1 = (const float*)&v1;
      const float* r2 = (const float*)&v2;
      const float* r3 = (const float*)&v3;
      #pragma unroll
      for (int j = 0; j < 4; ++j) {
        U4 u;
        u.v[0] = pkrtz(r0[j], r1[j]);
        u.v[1] = pkrtz(r2[j], r3[j]);
        *(H4*)&bT[(cg*4 + j)*36 + rg*4] = u.h;
      }
    }
    __syncthreads();
    {
      const int kc = l >> 4;
      f16x8 a_[2];
      #pragma unroll
      for (int m = 0; m < 2; ++m) {
        int mr = wm*32 + m*16 + (l&15);
        a_[m] = *(const f16x8*)&aT[mr*32 + (kc ^ (mr&3))*8];
      }
      #pragma unroll
      for (int n = 0; n < 4; ++n) {
        f16x8 bb = frag_b36(bT, wn*64 + n*16 + (l&15), kc);
        #pragma unroll
        for (int m = 0; m < 2; ++m) acc[m][n] = mfma16(a_[m], bb, acc[m][n]);
      }
    }
  }
  #pragma unroll
  for (int m = 0; m < 2; ++m)
    #pragma unroll
    for (int r = 0; r < 4; ++r) {
      int srow2 = mt*64 + wm*32 + m*16 + (l>>4)*4 + r;
      if (srow2 < cnt) {
        int tok = slot_tok[e*2048 + srow2];
        float wt = slot_w[e*2048 + srow2];
        #pragma unroll
        for (int n = 0; n < 4; ++n) {
          int col = nt*128 + wn*64 + n*16 + (l&15);
          atomicAdd(&out[(size_t)tok*2048 + col], wt*acc[m][n][r]);
        }
      }
    }
}

extern "C" void kernel_launch(void* const* d_in, const int* in_sizes, int n_in,
                              void* d_out, int out_size, void* d_ws, size_t ws_size,
                              hipStream_t stream) {
  const int*   positions = (const int*)d_in[0];
  const float* x   = (const float*)d_in[1];
  const float* wq  = (const float*)d_in[2];
  const float* wk  = (const float*)d_in[3];
  const float* wv  = (const float*)d_in[4];
  const float* wo  = (const float*)d_in[5];
  const float* wg  = (const float*)d_in[6];
  const float* w1  = (const float*)d_in[7];
  const float* w2  = (const float*)d_in[8];
  const float* w3  = (const float*)d_in[9];
  const float* ln_in   = (const float*)d_in[10];
  const float* ln_post = (const float*)d_in[11];

  float* moe_out   = (float*)d_out;
  float* resid_out = (float*)d_out + (size_t)4194304;

  char* ws = (char*)d_ws;
  _Float16* h_hi   = (_Float16*)(ws);
  _Float16* h_lo   = (_Float16*)(ws + 8388608);
  float*    qbuf   = (float*)(ws + 16777216);
  float*    kbuf   = (float*)(ws + 33554432);
  float*    vbuf   = (float*)(ws + 37748736);
  _Float16* o_hi   = (_Float16*)(ws + 41943040);
  _Float16* o_lo   = (_Float16*)(ws + 50331648);
  _Float16* h2     = (_Float16*)(ws + 58720256);
  float*    logits = (float*)(ws + 67108864);
  int*      counts = (int*)(ws + 67174400);
  int*      offs   = (int*)(ws + 67174656);
  int*      slot_tok = (int*)(ws + 67174912);
  float*    slot_w   = (float*)(ws + 67240448);
  _Float16* gbuf   = (_Float16*)ws;   // aliases h_hi/h_lo/qbuf (dead by MoE time)

  // zero-init K-split GEMM outputs; resid starts at x (o-proj accumulates on top)
  hipMemsetAsync(qbuf, 0, 16777216, stream);
  hipMemsetAsync(kbuf, 0, 4194304, stream);
  hipMemsetAsync(vbuf, 0, 4194304, stream);
  hipMemcpyAsync(resid_out, x, (size_t)4194304*4, hipMemcpyDeviceToDevice, stream);
  hipMemsetAsync(moe_out, 0, (size_t)4194304*4, stream);
  hipMemsetAsync(counts, 0, 32, stream);

  k_rmsnorm_split<<<2048, 256, 0, stream>>>(x, ln_in, h_hi, h_lo);
  k_gemm_ks<<<dim3(16,16,2), 256, 0, stream>>>(h_hi, h_lo, wq, 2048, 2048, qbuf);
  k_gemm_ks<<<dim3(4,16,4),  256, 0, stream>>>(h_hi, h_lo, wk,  512, 2048, kbuf);
  k_gemm_ks<<<dim3(4,16,4),  256, 0, stream>>>(h_hi, h_lo, wv,  512, 2048, vbuf);
  k_rope<<<dim3(2048,4), 256, 0, stream>>>(qbuf, positions, 16);
  k_rope<<<dim3(2048,1), 256, 0, stream>>>(kbuf, positions, 4);
  k_attn<<<dim3(32,16), 256, 0, stream>>>(qbuf, kbuf, vbuf, o_hi, o_lo);
  k_gemm_ks<<<dim3(16,16,2), 256, 0, stream>>>(o_hi, o_lo, wo, 2048, 2048, resid_out);
  k_postnorm_gate<<<2048, 256, 0, stream>>>(resid_out, ln_post, wg, h2, logits);
  k_route<<<8, 256, 0, stream>>>(logits, counts, slot_tok, slot_w);
  k_scan<<<1, 64, 0, stream>>>(counts, offs);
  k_moe1<<<16384, 256, 0, stream>>>(h2, w1, w3, counts, offs, slot_tok, gbuf);
  k_moe2<<<4096, 256, 0, stream>>>(gbuf, w2, counts, offs, slot_tok, slot_w, moe_out);
}

// Round 16
// 1111.264 us; speedup vs baseline: 2.1721x; 2.1721x over previous
//
#include <hip/hip_runtime.h>

typedef _Float16 f16x8 __attribute__((ext_vector_type(8)));
typedef _Float16 f16x2 __attribute__((ext_vector_type(2)));
typedef float f32x4 __attribute__((ext_vector_type(4)));

#define DEV __device__ __forceinline__

struct alignas(16) H8 { _Float16 h[8]; };
struct alignas(8)  H4 { _Float16 h[4]; };

union U8 { f16x2 v[4]; f16x8 x; H8 h; };
union U4 { f16x2 v[2]; H4 h; unsigned int u[2]; };

DEV f32x4 mfma16(f16x8 a, f16x8 b, f32x4 c) {
  return __builtin_amdgcn_mfma_f32_16x16x32_f16(a, b, c, 0, 0, 0);
}

DEV f16x2 pkrtz(float a, float b) {
  return __builtin_bit_cast(f16x2, __builtin_amdgcn_cvt_pkrtz(a, b));
}

// 8-wide f32 -> fp16 hi/lo split via packed converts (hi RTZ; lo captures residual)
DEV void split8v(const float* t, f16x8& hi, f16x8& lo) {
  U8 H_, L_;
  #pragma unroll
  for (int j = 0; j < 4; ++j) {
    f16x2 hh = pkrtz(t[2*j], t[2*j+1]);
    float r0 = t[2*j]   - (float)hh[0];
    float r1 = t[2*j+1] - (float)hh[1];
    H_.v[j] = hh;
    L_.v[j] = pkrtz(r0, r1);
  }
  hi = H_.x; lo = L_.x;
}

// pair split: 2 f32 -> hi f16x2 (RTZ) + lo f16x2 (residual)
DEV void packpair(float a, float b, f16x2& hi, f16x2& lo) {
  f16x2 hh = pkrtz(a, b);
  lo = pkrtz(a - (float)hh[0], b - (float)hh[1]);
  hi = hh;
}

// read 8 fp16 from 72-byte-stride bT layout (two b64 loads, 8B aligned)
DEV f16x8 frag_b36(const _Float16* b, int n, int kc) {
  const unsigned long long* p = (const unsigned long long*)(b + n*36 + kc*8);
  union { unsigned long long u[2]; f16x8 v; } r;
  r.u[0] = p[0]; r.u[1] = p[1];
  return r.v;
}

DEV float block_sum(float v, volatile float* red, int tid) {
  #pragma unroll
  for (int mm = 1; mm < 64; mm <<= 1) v += __shfl_xor(v, mm);
  if ((tid & 63) == 0) red[tid >> 6] = v;
  __syncthreads();
  return red[0] + red[1] + red[2] + red[3];
}

// ---------------- RMSNorm (input) -> fp16 hi/lo split ----------------
__global__ __launch_bounds__(256) void k_rmsnorm_split(
    const float* __restrict__ x, const float* __restrict__ w,
    _Float16* __restrict__ hi, _Float16* __restrict__ lo) {
  __shared__ float red[4];
  int row = blockIdx.x, tid = threadIdx.x;
  const float* xr = x + (size_t)row*2048 + tid*8;
  float xs[8];
  *(float4*)&xs[0] = *(const float4*)xr;
  *(float4*)&xs[4] = *(const float4*)(xr + 4);
  float ss = 0.f;
  #pragma unroll
  for (int j = 0; j < 8; ++j) ss += xs[j]*xs[j];
  float tot = block_sum(ss, red, tid);
  float sc = 1.0f / sqrtf(tot*(1.0f/2048.0f) + 1e-5f);
  const float* wr = w + tid*8;
  H8 ph, pl;
  #pragma unroll
  for (int j = 0; j < 8; ++j) {
    float o = xs[j]*sc*wr[j];
    _Float16 hh = (_Float16)o;
    ph.h[j] = hh; pl.h[j] = (_Float16)(o - (float)hh);
  }
  *(H8*)(hi + (size_t)row*2048 + tid*8) = ph;
  *(H8*)(lo + (size_t)row*2048 + tid*8) = pl;
}

// ---------------- dense split GEMM, K-split + atomic epilogue ----------------
// B staged via float4 row-contiguous loads (4 cols x 4 rows per thread).
__global__ __launch_bounds__(256) void k_gemm_ks(
    const _Float16* __restrict__ Ahi, const _Float16* __restrict__ Alo,
    const float* __restrict__ B, int N, int K,
    float* __restrict__ C) {
  const int tid = threadIdx.x;
  const int l = tid & 63, w = tid >> 6;
  const int wm = w >> 1, wn = w & 1;
  const int row0 = blockIdx.y * 128, col0 = blockIdx.x * 128;
  const int kz = K / gridDim.z;
  const int kbase = blockIdx.z * kz;

  __shared__ _Float16 aHi[128*32], aLo[128*32];
  __shared__ _Float16 bHi[128*36], bLo[128*36];

  f32x4 acc[4][4] = {};

  const int rS = tid >> 1, khalf = tid & 1;
  const int cg = tid & 31, rg = tid >> 5;   // B: 4 cols (cg*4), 4 rows (rg*4)

  for (int k0 = kbase; k0 < kbase + kz; k0 += 32) {
    __syncthreads();
    { // stage A (chunk-XOR swizzled)
      int c0 = khalf*2;
      int d0 = rS*32 + ((c0    ) ^ (rS&3))*8;
      int d1 = rS*32 + ((c0 + 1) ^ (rS&3))*8;
      const _Float16* ah = Ahi + (size_t)(row0 + rS)*K + k0 + khalf*16;
      const _Float16* al = Alo + (size_t)(row0 + rS)*K + k0 + khalf*16;
      *(H8*)&aHi[d0] = *(const H8*)ah;
      *(H8*)&aHi[d1] = *(const H8*)(ah + 8);
      *(H8*)&aLo[d0] = *(const H8*)al;
      *(H8*)&aLo[d1] = *(const H8*)(al + 8);
    }
    { // stage B: 4 float4 row-contiguous loads, split + transpose-pack
      const float* bp = B + (size_t)(k0 + rg*4)*N + col0 + cg*4;
      float4 v0 = *(const float4*)bp;
      float4 v1 = *(const float4*)(bp + N);
      float4 v2 = *(const float4*)(bp + 2*(size_t)N);
      float4 v3 = *(const float4*)(bp + 3*(size_t)N);
      const float* r0 = (const float*)&v0;
      const float* r1 = (const float*)&v1;
      const float* r2 = (const float*)&v2;
      const float* r3 = (const float*)&v3;
      #pragma unroll
      for (int j = 0; j < 4; ++j) {
        U4 hu, lu;
        packpair(r0[j], r1[j], hu.v[0], lu.v[0]);
        packpair(r2[j], r3[j], hu.v[1], lu.v[1]);
        int ei = (cg*4 + j)*36 + rg*4;
        *(H4*)&bHi[ei] = hu.h;
        *(H4*)&bLo[ei] = lu.h;
      }
    }
    __syncthreads();
    { // compute
      const int kc = l >> 4;
      f16x8 ah[4], al4[4];
      #pragma unroll
      for (int m = 0; m < 4; ++m) {
        int mr = wm*64 + m*16 + (l & 15);
        int cc = (kc ^ (mr & 3))*8;
        ah[m]  = *(const f16x8*)&aHi[mr*32 + cc];
        al4[m] = *(const f16x8*)&aLo[mr*32 + cc];
      }
      #pragma unroll
      for (int n = 0; n < 4; ++n) {
        int nr = wn*64 + n*16 + (l & 15);
        f16x8 bh = frag_b36(bHi, nr, kc);
        f16x8 bl = frag_b36(bLo, nr, kc);
        #pragma unroll
        for (int m = 0; m < 4; ++m) {
          acc[m][n] = mfma16(ah[m],  bh, acc[m][n]);
          acc[m][n] = mfma16(ah[m],  bl, acc[m][n]);
          acc[m][n] = mfma16(al4[m], bh, acc[m][n]);
        }
      }
    }
  }
  #pragma unroll
  for (int m = 0; m < 4; ++m)
    #pragma unroll
    for (int n = 0; n < 4; ++n)
      #pragma unroll
      for (int r = 0; r < 4; ++r) {
        int row = row0 + wm*64 + m*16 + (l>>4)*4 + r;
        int col = col0 + wn*64 + n*16 + (l&15);
        atomicAdd(&C[(size_t)row*N + col], acc[m][n][r]);
      }
}

// ---------------- RoPE (neox, in-place, f32) ----------------
__global__ __launch_bounds__(256) void k_rope(
    float* __restrict__ buf, const int* __restrict__ pos, int nh) {
  int s = blockIdx.x;
  int hh = blockIdx.y*4 + (threadIdx.x >> 6);
  int d = threadIdx.x & 63;
  float p = (float)pos[s];
  double ex = ((double)(2*d)/128.0) * 9.210340371976184; // log(10000)
  float pw = (float)exp(ex);
  float inv = 1.0f / pw;
  float ang = p * inv;
  float cs = cosf(ang), sn = sinf(ang);
  float* b = buf + (size_t)s*(nh*128) + hh*128 + d;
  float x1 = b[0], x2 = b[64];
  b[0]  = x1*cs - x2*sn;
  b[64] = x2*cs + x1*sn;
}

// ---------------- flash attention, fp16x2 split, causal GQA ----------------
__global__ __launch_bounds__(256) void k_attn(
    const float* __restrict__ q, const float* __restrict__ k,
    const float* __restrict__ v,
    _Float16* __restrict__ o_hi, _Float16* __restrict__ o_lo) {
  const int qt = gridDim.x - 1 - blockIdx.x;  // heavy causal tiles first
  const int h = blockIdx.y;
  const int tid = threadIdx.x, l = tid & 63, w = tid >> 6;
  const int qb = qt*64, qw = qb + w*16;
  const int kvh = h >> 2;

  __shared__ _Float16 kHi[32*128], kLo[32*128];
  __shared__ _Float16 vHi[128*32], vLo[128*32];  // transposed [d][kv]
  __shared__ _Float16 pHi[4][16*40], pLo[4][16*40];

  f16x8 qh[4], ql[4];
  {
    int qrow = qw + (l & 15);
    const float* qp = q + (size_t)qrow*2048 + h*128 + (l>>4)*8;
    #pragma unroll
    for (int c = 0; c < 4; ++c) {
      float t[8];
      *(float4*)&t[0] = *(const float4*)(qp + c*32);
      *(float4*)&t[4] = *(const float4*)(qp + c*32 + 4);
      split8v(t, qh[c], ql[c]);
    }
  }

  float mrun[4], lrun[4];
  f32x4 oacc[8] = {};
  #pragma unroll
  for (int r = 0; r < 4; ++r) { mrun[r] = -1e30f; lrun[r] = 0.f; }

  const int srow = tid >> 3, sc = (tid & 7)*2;

  for (int kv0 = 0; kv0 <= qb + 32; kv0 += 32) {
    __syncthreads();
    { // stage K (row-major, XOR swizzle) and V (transposed, XOR swizzle)
      const float* kp = k + (size_t)(kv0 + srow)*512 + kvh*128 + sc*8;
      const float* vp = v + (size_t)(kv0 + srow)*512 + kvh*128 + sc*8;
      #pragma unroll
      for (int cc = 0; cc < 2; ++cc) {
        int c = sc + cc;
        float tk[8];
        *(float4*)&tk[0] = *(const float4*)(kp + cc*8);
        *(float4*)&tk[4] = *(const float4*)(kp + cc*8 + 4);
        f16x8 hx, lx;
        split8v(tk, hx, lx);
        int di = srow*128 + (c ^ (srow & 7))*8;
        *(H8*)&kHi[di] = *(const H8*)&hx;
        *(H8*)&kLo[di] = *(const H8*)&lx;
        float tv_[8];
        *(float4*)&tv_[0] = *(const float4*)(vp + cc*8);
        *(float4*)&tv_[4] = *(const float4*)(vp + cc*8 + 4);
        #pragma unroll
        for (int j = 0; j < 8; ++j) {
          float x = tv_[j];
          _Float16 hh = (_Float16)x;
          _Float16 ll = (_Float16)(x - (float)hh);
          int d = c*8 + j;
          int vi = d*32 + (((srow>>3) ^ (d&3)))*8 + (srow & 7);
          vHi[vi] = hh; vLo[vi] = ll;
        }
      }
    }
    __syncthreads();
    if (kv0 <= qw + 15) {
      f32x4 s[2] = {};
      #pragma unroll
      for (int nt = 0; nt < 2; ++nt) {
        int krow = nt*16 + (l & 15);
        #pragma unroll
        for (int c = 0; c < 4; ++c) {
          int ch = (c*4 + (l>>4)) ^ (krow & 7);
          f16x8 bh = *(const f16x8*)&kHi[krow*128 + ch*8];
          f16x8 bl = *(const f16x8*)&kLo[krow*128 + ch*8];
          s[nt] = mfma16(qh[c], bh, s[nt]);
          s[nt] = mfma16(qh[c], bl, s[nt]);
          s[nt] = mfma16(ql[c], bh, s[nt]);
        }
      }
      const float SC = 0.08838834764831845f;
      float sv[2][4];
      #pragma unroll
      for (int nt = 0; nt < 2; ++nt)
        #pragma unroll
        for (int r = 0; r < 4; ++r) {
          float val = s[nt][r]*SC;
          int qg = qw + (l>>4)*4 + r;
          int kg = kv0 + nt*16 + (l & 15);
          sv[nt][r] = (kg > qg) ? -1e30f : val;
        }
      float tm[4];
      #pragma unroll
      for (int r = 0; r < 4; ++r) tm[r] = fmaxf(sv[0][r], sv[1][r]);
      #pragma unroll
      for (int mm = 1; mm < 16; mm <<= 1)
        #pragma unroll
        for (int r = 0; r < 4; ++r) tm[r] = fmaxf(tm[r], __shfl_xor(tm[r], mm));
      float alpha[4], rs[4];
      #pragma unroll
      for (int r = 0; r < 4; ++r) {
        float mn = fmaxf(mrun[r], tm[r]);
        alpha[r] = expf(mrun[r] - mn);
        mrun[r] = mn;
      }
      float pv[2][4];
      #pragma unroll
      for (int nt = 0; nt < 2; ++nt)
        #pragma unroll
        for (int r = 0; r < 4; ++r) pv[nt][r] = expf(sv[nt][r] - mrun[r]);
      #pragma unroll
      for (int r = 0; r < 4; ++r) rs[r] = pv[0][r] + pv[1][r];
      #pragma unroll
      for (int mm = 1; mm < 16; mm <<= 1)
        #pragma unroll
        for (int r = 0; r < 4; ++r) rs[r] += __shfl_xor(rs[r], mm);
      #pragma unroll
      for (int r = 0; r < 4; ++r) lrun[r] = lrun[r]*alpha[r] + rs[r];
      #pragma unroll
      for (int dt = 0; dt < 8; ++dt)
        #pragma unroll
        for (int r = 0; r < 4; ++r) oacc[dt][r] *= alpha[r];
      // P -> per-wave LDS (split), then read back as A-fragments
      #pragma unroll
      for (int nt = 0; nt < 2; ++nt)
        #pragma unroll
        for (int r = 0; r < 4; ++r) {
          float x = pv[nt][r];
          _Float16 hh = (_Float16)x;
          int qr = (l>>4)*4 + r, kc = nt*16 + (l & 15);
          pHi[w][qr*40 + kc] = hh;
          pLo[w][qr*40 + kc] = (_Float16)(x - (float)hh);
        }
      f16x8 pa = *(const f16x8*)&pHi[w][(l&15)*40 + (l>>4)*8];
      f16x8 pb = *(const f16x8*)&pLo[w][(l&15)*40 + (l>>4)*8];
      #pragma unroll
      for (int dt = 0; dt < 8; ++dt) {
        int d = dt*16 + (l & 15);
        int ch = ((l>>4) ^ (d & 3))*8;
        f16x8 vh = *(const f16x8*)&vHi[d*32 + ch];
        f16x8 vl = *(const f16x8*)&vLo[d*32 + ch];
        oacc[dt] = mfma16(pa, vh, oacc[dt]);
        oacc[dt] = mfma16(pa, vl, oacc[dt]);
        oacc[dt] = mfma16(pb, vh, oacc[dt]);
      }
    }
  }
  #pragma unroll
  for (int dt = 0; dt < 8; ++dt)
    #pragma unroll
    for (int r = 0; r < 4; ++r) {
      int qg = qw + (l>>4)*4 + r;
      float ov = oacc[dt][r] / lrun[r];
      _Float16 hh = (_Float16)ov;
      size_t idx = (size_t)qg*2048 + h*128 + dt*16 + (l&15);
      o_hi[idx] = hh;
      o_lo[idx] = (_Float16)(ov - (float)hh);
    }
}

// ---------------- post-attn RMSNorm + gate logits ----------------
__global__ __launch_bounds__(256) void k_postnorm_gate(
    const float* __restrict__ resid, const float* __restrict__ wln,
    const float* __restrict__ wg, _Float16* __restrict__ h2,
    float* __restrict__ logits) {
  __shared__ float red[4];
  __shared__ float red2[4][8];
  int row = blockIdx.x, tid = threadIdx.x;
  const float* xr = resid + (size_t)row*2048 + tid*8;
  float xs[8];
  *(float4*)&xs[0] = *(const float4*)xr;
  *(float4*)&xs[4] = *(const float4*)(xr + 4);
  float ss = 0.f;
  #pragma unroll
  for (int j = 0; j < 8; ++j) ss += xs[j]*xs[j];
  float tot = block_sum(ss, red, tid);
  float sc = 1.0f/sqrtf(tot*(1.0f/2048.0f) + 1e-5f);
  const float* wr = wln + tid*8;
  float hv[8];
  H8 ph;
  #pragma unroll
  for (int j = 0; j < 8; ++j) {
    hv[j] = xs[j]*sc*wr[j];
    ph.h[j] = (_Float16)hv[j];
  }
  *(H8*)(h2 + (size_t)row*2048 + tid*8) = ph;
  float lg[8] = {0,0,0,0,0,0,0,0};
  const float* wgp = wg + (size_t)tid*8*8;
  #pragma unroll
  for (int j = 0; j < 8; ++j)
    #pragma unroll
    for (int e = 0; e < 8; ++e) lg[e] += hv[j]*wgp[j*8 + e];
  #pragma unroll
  for (int mm = 1; mm < 64; mm <<= 1)
    #pragma unroll
    for (int e = 0; e < 8; ++e) lg[e] += __shfl_xor(lg[e], mm);
  if ((tid & 63) == 0)
    #pragma unroll
    for (int e = 0; e < 8; ++e) red2[tid>>6][e] = lg[e];
  __syncthreads();
  if (tid < 8)
    logits[(size_t)row*8 + tid] = red2[0][tid]+red2[1][tid]+red2[2][tid]+red2[3][tid];
}

// ---------------- routing: top-2, slot lists ----------------
__global__ __launch_bounds__(256) void k_route(
    const float* __restrict__ logits, int* __restrict__ counts,
    int* __restrict__ slot_tok, float* __restrict__ slot_w) {
  int t = blockIdx.x*256 + threadIdx.x;
  if (t >= 2048) return;
  float lg[8];
  #pragma unroll
  for (int e = 0; e < 8; ++e) lg[e] = logits[t*8 + e];
  int a = 0; float la = lg[0];
  #pragma unroll
  for (int e = 1; e < 8; ++e) if (lg[e] > la) { la = lg[e]; a = e; }
  int b = -1; float lb = -3e38f;
  #pragma unroll
  for (int e = 0; e < 8; ++e) if (e != a && lg[e] > lb) { lb = lg[e]; b = e; }
  float wa = 1.f/(1.f + expf(lb - la));
  float wb = 1.f - wa;
  int sa = atomicAdd(&counts[a], 1);
  slot_tok[a*2048 + sa] = t; slot_w[a*2048 + sa] = wa;
  int sb = atomicAdd(&counts[b], 1);
  slot_tok[b*2048 + sb] = t; slot_w[b*2048 + sb] = wb;
}

__global__ void k_scan(const int* __restrict__ counts, int* __restrict__ offs) {
  if (threadIdx.x == 0) {
    int o_ = 0;
    #pragma unroll
    for (int e = 0; e < 8; ++e) { offs[e] = o_; o_ += counts[e]; }
  }
}

// ---------------- MoE GEMM1: g = silu(A@w1)*(A@w3) ----------------
// Proven 335us config (round 12): BM=128, dual-BN=64, BK=32, e|mt|nt,
// 2-barrier loop, float4 B staging. No cross-barrier register state.
__global__ __launch_bounds__(256) void k_moe1(
    const _Float16* __restrict__ h2, const float* __restrict__ w1,
    const float* __restrict__ w3, const int* __restrict__ counts,
    const int* __restrict__ offs, const int* __restrict__ slot_tok,
    _Float16* __restrict__ g) {
  int bid = blockIdx.x;
  int e = bid >> 10, mt = (bid >> 6) & 15, nt = bid & 63;
  int cnt = counts[e];
  if (mt*128 >= cnt) return;
  const int tid = threadIdx.x, l = tid & 63, w = tid >> 6;
  const int wm = w >> 1, wn = w & 1;
  __shared__ _Float16 aT[128*32];
  __shared__ _Float16 b1[64*36], b3[64*36];
  const int rS = tid >> 1, khalf = tid & 1;
  int slot = mt*128 + rS;
  int tok = (slot < cnt) ? slot_tok[e*2048 + slot] : slot_tok[e*2048];
  const _Float16* arow = h2 + (size_t)tok*2048;
  const int cg = tid & 15, rg = tid >> 4;   // B: 4 cols (cg*4), 2 rows (rg*2)
  const float* w1p = w1 + (size_t)e*2048*4096 + nt*64 + cg*4 + (size_t)rg*2*4096;
  const float* w3p = w3 + (size_t)e*2048*4096 + nt*64 + cg*4 + (size_t)rg*2*4096;
  f32x4 acc1[4][2] = {}, acc3[4][2] = {};
  for (int k0 = 0; k0 < 2048; k0 += 32) {
    __syncthreads();
    {
      const _Float16* ap = arow + k0 + khalf*16;
      int c0 = khalf*2;
      *(H8*)&aT[rS*32 + ((c0  )^(rS&3))*8] = *(const H8*)ap;
      *(H8*)&aT[rS*32 + ((c0+1)^(rS&3))*8] = *(const H8*)(ap + 8);
    }
    { // stage B dual: 2 float4 per matrix (rows rg*2, rg*2+1)
      const float* p1 = w1p + (size_t)k0*4096;
      float4 a0 = *(const float4*)p1;
      float4 a1 = *(const float4*)(p1 + 4096);
      const float* p3 = w3p + (size_t)k0*4096;
      float4 c0_ = *(const float4*)p3;
      float4 c1 = *(const float4*)(p3 + 4096);
      const float* x0 = (const float*)&a0;
      const float* x1 = (const float*)&a1;
      const float* y0 = (const float*)&c0_;
      const float* y1 = (const float*)&c1;
      #pragma unroll
      for (int j = 0; j < 4; ++j) {
        int ei = (cg*4 + j)*36 + rg*2;
        *(f16x2*)&b1[ei] = pkrtz(x0[j], x1[j]);
        *(f16x2*)&b3[ei] = pkrtz(y0[j], y1[j]);
      }
    }
    __syncthreads();
    {
      const int kc = l >> 4;
      f16x8 a_[4];
      #pragma unroll
      for (int m = 0; m < 4; ++m) {
        int mr = wm*64 + m*16 + (l & 15);
        a_[m] = *(const f16x8*)&aT[mr*32 + (kc ^ (mr&3))*8];
      }
      #pragma unroll
      for (int n = 0; n < 2; ++n) {
        int nr = wn*32 + n*16 + (l & 15);
        f16x8 bb1 = frag_b36(b1, nr, kc);
        f16x8 bb3 = frag_b36(b3, nr, kc);
        #pragma unroll
        for (int m = 0; m < 4; ++m) {
          acc1[m][n] = mfma16(a_[m], bb1, acc1[m][n]);
          acc3[m][n] = mfma16(a_[m], bb3, acc3[m][n]);
        }
      }
    }
  }
  int ge = offs[e];
  #pragma unroll
  for (int m = 0; m < 4; ++m)
    #pragma unroll
    for (int n = 0; n < 2; ++n)
      #pragma unroll
      for (int r = 0; r < 4; ++r) {
        int srow2 = mt*128 + wm*64 + m*16 + (l>>4)*4 + r;
        if (srow2 < cnt) {
          float x1 = acc1[m][n][r], x3 = acc3[m][n][r];
          float gg = (x1/(1.f + expf(-x1)))*x3;
          int col = nt*64 + wn*32 + n*16 + (l&15);
          g[(size_t)(ge + srow2)*4096 + col] = (_Float16)gg;
        }
      }
}

// ---------------- MoE GEMM2: out[tok] += wgt * (g@w2) ----------------
// Round-12 proven loop (BM=128, BN=128, BK=32, float4 B stage) + K-split:
// blockIdx.y picks K half; epilogue already atomic (fills the grid, 512->1024
// live blocks).
__global__ __launch_bounds__(256) void k_moe2(
    const _Float16* __restrict__ g, const float* __restrict__ w2,
    const int* __restrict__ counts, const int* __restrict__ offs,
    const int* __restrict__ slot_tok, const float* __restrict__ slot_w,
    float* __restrict__ out) {
  int bid = blockIdx.x;
  int e = bid >> 8, mt = (bid >> 4) & 15, nt = bid & 15;
  int cnt = counts[e];
  if (mt*128 >= cnt) return;
  const int tid = threadIdx.x, l = tid & 63, w = tid >> 6;
  const int wm = w >> 1, wn = w & 1;
  __shared__ _Float16 aT[128*32];
  __shared__ _Float16 bT[128*36];
  const int rS = tid >> 1, khalf = tid & 1;
  int ge = offs[e];
  int slot = mt*128 + rS;
  const _Float16* arow = g + (size_t)(ge + (slot < cnt ? slot : 0))*4096;
  const int cg = tid & 31, rg = tid >> 5;   // B: 4 cols (cg*4), 4 rows (rg*4)
  const float* w2p = w2 + (size_t)e*4096*2048 + nt*128 + cg*4 + (size_t)rg*4*2048;
  const int kbase = blockIdx.y * 2048;
  f32x4 acc[4][4] = {};
  for (int k0 = kbase; k0 < kbase + 2048; k0 += 32) {
    __syncthreads();
    {
      const _Float16* ap = arow + k0 + khalf*16;
      int c0 = khalf*2;
      *(H8*)&aT[rS*32 + ((c0  )^(rS&3))*8] = *(const H8*)ap;
      *(H8*)&aT[rS*32 + ((c0+1)^(rS&3))*8] = *(const H8*)(ap + 8);
    }
    { // stage B: 4 float4 (rows rg*4..+3), transpose-pack to b36
      const float* p = w2p + (size_t)k0*2048;
      float4 v0 = *(const float4*)p;
      float4 v1 = *(const float4*)(p + 2048);
      float4 v2 = *(const float4*)(p + 2*(size_t)2048);
      float4 v3 = *(const float4*)(p + 3*(size_t)2048);
      const float* r0 = (const float*)&v0;
      const float* r1 = (const float*)&v1;
      const float* r2 = (const float*)&v2;
      const float* r3 = (const float*)&v3;
      #pragma unroll
      for (int j = 0; j < 4; ++j) {
        U4 u;
        u.v[0] = pkrtz(r0[j], r1[j]);
        u.v[1] = pkrtz(r2[j], r3[j]);
        *(H4*)&bT[(cg*4 + j)*36 + rg*4] = u.h;
      }
    }
    __syncthreads();
    {
      const int kc = l >> 4;
      f16x8 a_[4];
      #pragma unroll
      for (int m = 0; m < 4; ++m) {
        int mr = wm*64 + m*16 + (l&15);
        a_[m] = *(const f16x8*)&aT[mr*32 + (kc ^ (mr&3))*8];
      }
      #pragma unroll
      for (int n = 0; n < 4; ++n) {
        f16x8 bb = frag_b36(bT, wn*64 + n*16 + (l&15), kc);
        #pragma unroll
        for (int m = 0; m < 4; ++m) acc[m][n] = mfma16(a_[m], bb, acc[m][n]);
      }
    }
  }
  #pragma unroll
  for (int m = 0; m < 4; ++m)
    #pragma unroll
    for (int r = 0; r < 4; ++r) {
      int srow2 = mt*128 + wm*64 + m*16 + (l>>4)*4 + r;
      if (srow2 < cnt) {
        int tok = slot_tok[e*2048 + srow2];
        float wt = slot_w[e*2048 + srow2];
        #pragma unroll
        for (int n = 0; n < 4; ++n) {
          int col = nt*128 + wn*64 + n*16 + (l&15);
          atomicAdd(&out[(size_t)tok*2048 + col], wt*acc[m][n][r]);
        }
      }
    }
}

extern "C" void kernel_launch(void* const* d_in, const int* in_sizes, int n_in,
                              void* d_out, int out_size, void* d_ws, size_t ws_size,
                              hipStream_t stream) {
  const int*   positions = (const int*)d_in[0];
  const float* x   = (const float*)d_in[1];
  const float* wq  = (const float*)d_in[2];
  const float* wk  = (const float*)d_in[3];
  const float* wv  = (const float*)d_in[4];
  const float* wo  = (const float*)d_in[5];
  const float* wg  = (const float*)d_in[6];
  const float* w1  = (const float*)d_in[7];
  const float* w2  = (const float*)d_in[8];
  const float* w3  = (const float*)d_in[9];
  const float* ln_in   = (const float*)d_in[10];
  const float* ln_post = (const float*)d_in[11];

  float* moe_out   = (float*)d_out;
  float* resid_out = (float*)d_out + (size_t)4194304;

  char* ws = (char*)d_ws;
  _Float16* h_hi   = (_Float16*)(ws);
  _Float16* h_lo   = (_Float16*)(ws + 8388608);
  float*    qbuf   = (float*)(ws + 16777216);
  float*    kbuf   = (float*)(ws + 33554432);
  float*    vbuf   = (float*)(ws + 37748736);
  _Float16* o_hi   = (_Float16*)(ws + 41943040);
  _Float16* o_lo   = (_Float16*)(ws + 50331648);
  _Float16* h2     = (_Float16*)(ws + 58720256);
  float*    logits = (float*)(ws + 67108864);
  int*      counts = (int*)(ws + 67174400);
  int*      offs   = (int*)(ws + 67174656);
  int*      slot_tok = (int*)(ws + 67174912);
  float*    slot_w   = (float*)(ws + 67240448);
  _Float16* gbuf   = (_Float16*)ws;   // aliases h_hi/h_lo/qbuf (dead by MoE time)

  // zero-init K-split GEMM outputs; resid starts at x (o-proj accumulates on top)
  hipMemsetAsync(qbuf, 0, 16777216, stream);
  hipMemsetAsync(kbuf, 0, 4194304, stream);
  hipMemsetAsync(vbuf, 0, 4194304, stream);
  hipMemcpyAsync(resid_out, x, (size_t)4194304*4, hipMemcpyDeviceToDevice, stream);
  hipMemsetAsync(moe_out, 0, (size_t)4194304*4, stream);
  hipMemsetAsync(counts, 0, 32, stream);

  k_rmsnorm_split<<<2048, 256, 0, stream>>>(x, ln_in, h_hi, h_lo);
  k_gemm_ks<<<dim3(16,16,2), 256, 0, stream>>>(h_hi, h_lo, wq, 2048, 2048, qbuf);
  k_gemm_ks<<<dim3(4,16,4),  256, 0, stream>>>(h_hi, h_lo, wk,  512, 2048, kbuf);
  k_gemm_ks<<<dim3(4,16,4),  256, 0, stream>>>(h_hi, h_lo, wv,  512, 2048, vbuf);
  k_rope<<<dim3(2048,4), 256, 0, stream>>>(qbuf, positions, 16);
  k_rope<<<dim3(2048,1), 256, 0, stream>>>(kbuf, positions, 4);
  k_attn<<<dim3(32,16), 256, 0, stream>>>(qbuf, kbuf, vbuf, o_hi, o_lo);
  k_gemm_ks<<<dim3(16,16,2), 256, 0, stream>>>(o_hi, o_lo, wo, 2048, 2048, resid_out);
  k_postnorm_gate<<<2048, 256, 0, stream>>>(resid_out, ln_post, wg, h2, logits);
  k_route<<<8, 256, 0, stream>>>(logits, counts, slot_tok, slot_w);
  k_scan<<<1, 64, 0, stream>>>(counts, offs);
  k_moe1<<<8192, 256, 0, stream>>>(h2, w1, w3, counts, offs, slot_tok, gbuf);
  k_moe2<<<dim3(2048,2), 256, 0, stream>>>(gbuf, w2, counts, offs, slot_tok, slot_w, moe_out);
}